// Round 8
// baseline (140.396 us; speedup 1.0000x reference)
//
#include <hip/hip_runtime.h>

// ---------------------------------------------------------------------------
// MultiheadAttention (B=2, S=2048, E=1024, H=16, D=64, MAX_DIST=4, causal)
//   1. f2bf converts (x once; 4 weights fused)
//   2. proj3: kh=[bs][e], qh=[bs][e] (*0.125), vt=[e][bs]
//   3. flash attention v8: 32x32x16 MFMA, 4 waves x 32 q-rows (128-q blocks),
//      split-K units (<=16 k-tiles, LPT), in-register P via cvt_pk+permlane32,
//      XOR-swizzled K/V dbuf, defer-max. 38.8KB LDS -> 4 blocks/CU.
//   4. combine partials -> ao
//   5. out = ao @ Wo^T -> fp32
// ---------------------------------------------------------------------------

using short8   = __attribute__((ext_vector_type(8))) short;
using floatx4  = __attribute__((ext_vector_type(4))) float;
using floatx16 = __attribute__((ext_vector_type(16))) float;
using float4v  = __attribute__((ext_vector_type(4))) float;
using ushort4v = __attribute__((ext_vector_type(4))) unsigned short;
using uint2v   = __attribute__((ext_vector_type(2))) unsigned int;
using uint4v   = __attribute__((ext_vector_type(4))) unsigned int;

#define LOG2E 1.4426950408889634f

__device__ __forceinline__ unsigned short f2bf(float f) {
  unsigned u = __float_as_uint(f);
  return (unsigned short)((u + 0x7FFFu + ((u >> 16) & 1u)) >> 16);  // RNE
}
__device__ __forceinline__ float bf2f(unsigned short s) {
  return __uint_as_float(((unsigned)s) << 16);
}
__device__ __forceinline__ unsigned cvt_pk_bf16(float lo, float hi) {
  unsigned r;
  asm("v_cvt_pk_bf16_f32 %0, %1, %2" : "=v"(r) : "v"(lo), "v"(hi));
  return r;
}
__device__ __forceinline__ void gload_lds16(const void* g, void* l) {
  __builtin_amdgcn_global_load_lds(
      (const __attribute__((address_space(1))) unsigned int*)g,
      (__attribute__((address_space(3))) unsigned int*)l, 16, 0, 0);
}

// --------------------------- fp32 -> bf16 convert ---------------------------
__global__ void f2bf_kern(const float* __restrict__ in,
                          unsigned short* __restrict__ out, int n4) {
  int i = blockIdx.x * 256 + threadIdx.x;
  if (i >= n4) return;
  float4v v = ((const float4v*)in)[i];
  ushort4v o;
  o[0] = f2bf(v[0]); o[1] = f2bf(v[1]); o[2] = f2bf(v[2]); o[3] = f2bf(v[3]);
  ((ushort4v*)out)[i] = o;
}

__global__ void f2bfW_kern(const float* __restrict__ w0, unsigned short* o0,
                           const float* __restrict__ w1, unsigned short* o1,
                           const float* __restrict__ w2, unsigned short* o2,
                           const float* __restrict__ w3, unsigned short* o3) {
  int i = blockIdx.x * 256 + threadIdx.x;
  const float* in;
  unsigned short* out;
  switch (blockIdx.y) {
    case 0: in = w0; out = o0; break;
    case 1: in = w1; out = o1; break;
    case 2: in = w2; out = o2; break;
    default: in = w3; out = o3; break;
  }
  float4v v = ((const float4v*)in)[i];
  ushort4v o;
  o[0] = f2bf(v[0]); o[1] = f2bf(v[1]); o[2] = f2bf(v[2]); o[3] = f2bf(v[3]);
  ((ushort4v*)out)[i] = o;
}

// ------------------------------ GEMM core (NT) ------------------------------
__device__ __forceinline__ void gemm_core(
    const unsigned short* __restrict__ A, const unsigned short* __restrict__ B,
    void* __restrict__ Cv, int N, int K, int mBase, int nBase, float alpha,
    bool outbf, unsigned short* As, unsigned short* Bs) {
  const int tid = threadIdx.x;
  const int lane = tid & 63;
  const int w = tid >> 6;
  const int wr = w >> 1, wc = w & 1;
  const int lr = lane & 15, lg = lane >> 4;

  floatx4 acc[4][4] = {};

  for (int k0 = 0; k0 < K; k0 += 32) {
#pragma unroll
    for (int i = 0; i < 2; ++i) {
      int idx = i * 256 + tid;
      int row = idx >> 2, c8 = (idx & 3) * 8;
      gload_lds16(A + (size_t)(mBase + row) * K + (k0 + c8), As + idx * 8);
      gload_lds16(B + (size_t)(nBase + row) * K + (k0 + c8), Bs + idx * 8);
    }
    __syncthreads();
    short8 af[4], bfr[4];
#pragma unroll
    for (int mf = 0; mf < 4; ++mf)
      af[mf] = *(const short8*)(As + (wr * 64 + mf * 16 + lr) * 32 + lg * 8);
#pragma unroll
    for (int nf = 0; nf < 4; ++nf)
      bfr[nf] = *(const short8*)(Bs + (wc * 64 + nf * 16 + lr) * 32 + lg * 8);
#pragma unroll
    for (int mf = 0; mf < 4; ++mf)
#pragma unroll
      for (int nf = 0; nf < 4; ++nf)
        acc[mf][nf] = __builtin_amdgcn_mfma_f32_16x16x32_bf16(
            af[mf], bfr[nf], acc[mf][nf], 0, 0, 0);
    __syncthreads();
  }

#pragma unroll
  for (int mf = 0; mf < 4; ++mf)
#pragma unroll
    for (int nf = 0; nf < 4; ++nf)
#pragma unroll
      for (int r = 0; r < 4; ++r) {
        size_t row = (size_t)mBase + wr * 64 + mf * 16 + lg * 4 + r;
        size_t col = (size_t)nBase + wc * 64 + nf * 16 + lr;
        float v = acc[mf][nf][r] * alpha;
        if (outbf)
          ((unsigned short*)Cv)[row * (size_t)N + col] = f2bf(v);
        else
          ((float*)Cv)[row * (size_t)N + col] = v;
      }
}

__global__ __launch_bounds__(256, 2) void proj3_kern(
    const unsigned short* __restrict__ xbf, const unsigned short* __restrict__ wkb,
    unsigned short* __restrict__ khb,
    const unsigned short* __restrict__ wqb, unsigned short* __restrict__ qhb,
    const unsigned short* __restrict__ wvb, unsigned short* __restrict__ vtb) {
  __shared__ alignas(16) unsigned short As[128 * 32];
  __shared__ alignas(16) unsigned short Bs[128 * 32];
  int z = blockIdx.z;
  if (z == 0)
    gemm_core(xbf, wkb, khb, 1024, 1024, blockIdx.y * 128, blockIdx.x * 128,
              1.0f, true, As, Bs);
  else if (z == 1)
    gemm_core(xbf, wqb, qhb, 1024, 1024, blockIdx.y * 128, blockIdx.x * 128,
              0.125f, true, As, Bs);
  else
    gemm_core(wvb, xbf, vtb, 4096, 1024, blockIdx.x * 128, blockIdx.y * 128,
              1.0f, true, As, Bs);
}

__global__ __launch_bounds__(256, 2) void gemm_out_kern(
    const unsigned short* __restrict__ A, const unsigned short* __restrict__ B,
    float* __restrict__ C) {
  __shared__ alignas(16) unsigned short As[128 * 32];
  __shared__ alignas(16) unsigned short Bs[128 * 32];
  gemm_core(A, B, C, 1024, 1024, blockIdx.y * 128, blockIdx.x * 128, 1.0f,
            false, As, Bs);
}

// ---------------------------- flash attention v8 ----------------------------
// Grid (32 hb, 24 units). Block = 4 waves, wave w owns q rows
// [i*128 + w*32, +32) (two adjacent q-tiles per block). 32x32x16 MFMA.
// Unit decode (LPT desc): u<8: chunk0 of pair i=8+u (k 0..15, partial);
// u=8: single i=7; u=9: chunk1 i=15; u>=10: j=(u-10)>>1, even: single i=6-j,
// odd: chunk1 i=14-j (k 16..2i+1).
__global__ __launch_bounds__(256, 4) void attn_kern(
    const unsigned short* __restrict__ qh,   // [4096][1024], pre-scaled
    const unsigned short* __restrict__ kh,   // [4096][1024]
    const unsigned short* __restrict__ vt,   // [1024][4096]
    const float* __restrict__ pp,            // [64][9]
    unsigned short* __restrict__ ao,         // [4096][1024]
    unsigned short* __restrict__ opart,      // [512][128][64] bf16 unnorm
    float* __restrict__ mbuf,                // [512][128]
    float* __restrict__ lbuf) {              // [512][128]
  __shared__ alignas(16) char smem[39680];
  unsigned short* Aq = (unsigned short*)smem;            // Q rows 0-63 / K-buf1
  unsigned short* Bq = (unsigned short*)(smem + 8192);   // Q rows 64-127 / V-buf1
  unsigned short* Ck = (unsigned short*)(smem + 16384);  // K-buf0
  unsigned short* Dv = (unsigned short*)(smem + 24576);  // V-buf0
  float* biasS = (float*)(smem + 32768);                 // [128][9]
  float* ppS   = (float*)(smem + 37376);                 // [9][64]

  const int tid = threadIdx.x;
  const int lane = tid & 63;
  const int w = tid >> 6;        // 0..3
  const int l31 = lane & 31, hi = lane >> 5;
  const int hb = blockIdx.x;
  const int h = hb & 15, b = hb >> 4;
  const int u = blockIdx.y;

  int i, k0, k1;
  bool partial;
  if (u < 8)       { i = 8 + u;  k0 = 0;  k1 = 16;        partial = true;  }
  else if (u == 8) { i = 7;      k0 = 0;  k1 = 16;        partial = false; }
  else if (u == 9) { i = 15;     k0 = 16; k1 = 32;        partial = true;  }
  else {
    int j = (u - 10) >> 1;
    if (((u - 10) & 1) == 0) { i = 6 - j;  k0 = 0;  k1 = 2 * i + 2; partial = false; }
    else                     { i = 14 - j; k0 = 16; k1 = 2 * i + 2; partial = true;  }
  }
  const int qunit = i * 128;
  const size_t grow = (size_t)b * 2048 + qunit;
  const int wqmin = qunit + w * 32;       // wave q-range [wqmin, wqmin+31]
  const int q_glob = wqmin + l31;         // this lane's q (l31-space)
  const int lrow = w * 32 + l31;          // local bias row

  const unsigned short* khB = kh + ((size_t)b * 2048) * 1024 + h * 64;
  const unsigned short* vtB = vt + ((size_t)h * 64) * 4096 + b * 2048;

  auto stage_kv = [&](int kbase, unsigned short* Kd, unsigned short* Vd) {
#pragma unroll
    for (int t = 0; t < 2; ++t) {
      int idx = t * 256 + tid;
      int row = idx >> 3, pc = idx & 7;
      int cl = pc ^ (row & 7);  // pre-swizzled global source
      gload_lds16(khB + ((size_t)(kbase + row) << 10) + cl * 8, Kd + idx * 8);
      gload_lds16(vtB + ((size_t)row << 12) + kbase + cl * 8, Vd + idx * 8);
    }
  };

  // prologue: stage Q (128 rows, linear) + pp + first K/V tile
#pragma unroll
  for (int t = 0; t < 4; ++t) {
    int idx = t * 256 + tid;
    int row = idx >> 3, pc = idx & 7;
    unsigned short* dst = (row < 64) ? (Aq + row * 64 + pc * 8)
                                     : (Bq + (row - 64) * 64 + pc * 8);
    gload_lds16(qh + (grow + row) * 1024 + h * 64 + pc * 8, dst);
  }
  for (int idx = tid; idx < 576; idx += 256) {
    int r = idx >> 6, d = idx & 63;
    ppS[r * 64 + d] = pp[d * 9 + r];
  }
  stage_kv(k0 * 64, Ck, Dv);
  __syncthreads();

  // Q fragments: lane holds Q[q = w*32+l31][d = c*16 + hi*8 + j]
  const unsigned short* Qreg = (w < 2) ? Aq : Bq;
  const int qlrow = (w & 1) * 32 + l31;
  short8 aq[4];
#pragma unroll
  for (int c = 0; c < 4; ++c)
    aq[c] = *(const short8*)(Qreg + qlrow * 64 + c * 16 + hi * 8);

  // rel-pos bias: biasS[row][r] = sum_d qh_scaled[row][d] * p[d][r]
  for (int idx = tid; idx < 1152; idx += 256) {
    int row = idx / 9, r = idx - row * 9;
    const unsigned short* qrow =
        (row < 64) ? (Aq + row * 64) : (Bq + (row - 64) * 64);
    const float* pr = ppS + r * 64;
    float s = 0.f;
#pragma unroll
    for (int d8 = 0; d8 < 8; ++d8) {
      short8 qv = *(const short8*)(qrow + d8 * 8);
#pragma unroll
      for (int jj = 0; jj < 8; ++jj)
        s += bf2f((unsigned short)qv[jj]) * pr[d8 * 8 + jj];
    }
    biasS[row * 9 + r] = s;
  }
  __syncthreads();  // Q/ppS done -> Aq/Bq become K/V buf-1

  const float b8 = biasS[lrow * 9 + 8];

  float m_run = -1e30f, l_run = 0.f;
  floatx16 o0 = {}, o1 = {};

  for (int kt = k0; kt < k1; ++kt) {
    const int kbase = kt * 64;
    const int cur = (kt - k0) & 1;
    unsigned short* Kc = cur ? Aq : Ck;
    unsigned short* Vc = cur ? Bq : Dv;
    if (kt + 1 < k1) stage_kv(kbase + 64, cur ? Ck : Aq, cur ? Dv : Bq);

    if (kbase <= wqmin + 31) {  // wave has live work in this tile
      const bool live1 = (kbase + 32 <= wqmin + 31);
      floatx16 sa0 = {}, sa1 = {};

      __builtin_amdgcn_s_setprio(1);
#pragma unroll
      for (int c = 0; c < 4; ++c) {
        short8 ak = *(const short8*)(Kc + l31 * 64 +
                                     (((c * 2 + hi) ^ (l31 & 7)) * 8));
        sa0 = __builtin_amdgcn_mfma_f32_32x32x16_bf16(ak, aq[c], sa0, 0, 0, 0);
      }
      if (live1) {
#pragma unroll
        for (int c = 0; c < 4; ++c) {
          short8 ak = *(const short8*)(Kc + (32 + l31) * 64 +
                                       (((c * 2 + hi) ^ (l31 & 7)) * 8));
          sa1 = __builtin_amdgcn_mfma_f32_32x32x16_bf16(ak, aq[c], sa1, 0, 0, 0);
        }
      }
      __builtin_amdgcn_s_setprio(0);

      // bias + causal mask per k-half
      const bool far0 = (wqmin >= kbase + 35);
      const bool far1 = (wqmin >= kbase + 67);
      if (!far0) {
#pragma unroll
        for (int r = 0; r < 16; ++r) {
          int kl = (r & 3) + 8 * ((r >> 2) & 3) + 4 * hi;
          int dq = q_glob - (kbase + kl);
          if (dq < 0) sa0[r] = -1e30f;
          else sa0[r] += biasS[lrow * 9 + (dq > 4 ? 8 : dq + 4)];
        }
      }
      if (live1 && !far1) {
#pragma unroll
        for (int r = 0; r < 16; ++r) {
          int kl = (r & 3) + 8 * ((r >> 2) & 3) + 4 * hi;
          int dq = q_glob - (kbase + 32 + kl);
          if (dq < 0) sa1[r] = -1e30f;
          else sa1[r] += biasS[lrow * 9 + (dq > 4 ? 8 : dq + 4)];
        }
      }

      // tile max (per-q; lanes l31 and l31+32 agree after the xor-32)
      float t0 = -1e30f;
#pragma unroll
      for (int r = 0; r < 16; ++r) t0 = fmaxf(t0, sa0[r]);
      if (far0) t0 += b8;
      float mx = t0;
      if (live1) {
        float t1 = -1e30f;
#pragma unroll
        for (int r = 0; r < 16; ++r) t1 = fmaxf(t1, sa1[r]);
        if (far1) t1 += b8;
        mx = fmaxf(mx, t1);
      }
      mx = fmaxf(mx, __shfl_xor(mx, 32, 64));

      // defer-max (THR=8)
      if (__any(mx > m_run + 8.f)) {
        float mn = fmaxf(m_run, mx);
        float al = __builtin_amdgcn_exp2f((m_run - mn) * LOG2E);
        m_run = mn;
        l_run *= al;
#pragma unroll
        for (int r = 0; r < 16; ++r) {
          float alo = __shfl(al, (r & 3) + 8 * ((r >> 2) & 3) + 4 * hi, 64);
          o0[r] *= alo;
          o1[r] *= alo;
        }
      }

      // P = exp(S + bias - m) in-register -> PV via cvt_pk + permlane32_swap
      float rs = 0.f;
      __builtin_amdgcn_s_setprio(1);
      {
        const float c1 = ((far0 ? b8 : 0.f) - m_run) * LOG2E;
#pragma unroll
        for (int ks = 0; ks < 2; ++ks) {
          float p0 = __builtin_amdgcn_exp2f(fmaf(sa0[8 * ks + 0], LOG2E, c1));
          float p1 = __builtin_amdgcn_exp2f(fmaf(sa0[8 * ks + 1], LOG2E, c1));
          float p2 = __builtin_amdgcn_exp2f(fmaf(sa0[8 * ks + 2], LOG2E, c1));
          float p3 = __builtin_amdgcn_exp2f(fmaf(sa0[8 * ks + 3], LOG2E, c1));
          float p4 = __builtin_amdgcn_exp2f(fmaf(sa0[8 * ks + 4], LOG2E, c1));
          float p5 = __builtin_amdgcn_exp2f(fmaf(sa0[8 * ks + 5], LOG2E, c1));
          float p6 = __builtin_amdgcn_exp2f(fmaf(sa0[8 * ks + 6], LOG2E, c1));
          float p7 = __builtin_amdgcn_exp2f(fmaf(sa0[8 * ks + 7], LOG2E, c1));
          rs += ((p0 + p1) + (p2 + p3)) + ((p4 + p5) + (p6 + p7));
          unsigned P00 = cvt_pk_bf16(p0, p1);
          unsigned P01 = cvt_pk_bf16(p2, p3);
          unsigned P10 = cvt_pk_bf16(p4, p5);
          unsigned P11 = cvt_pk_bf16(p6, p7);
          uint2v s0 = __builtin_amdgcn_permlane32_swap(P00, P10, false, false);
          uint2v s1 = __builtin_amdgcn_permlane32_swap(P01, P11, false, false);
          uint4v fr;
          fr[0] = s0[0]; fr[1] = s1[0]; fr[2] = s0[1]; fr[3] = s1[1];
          short8 af = *(short8*)&fr;
          int ch = ((ks * 2 + hi) ^ (l31 & 7)) * 8;
          short8 bv0 = *(const short8*)(Vc + l31 * 64 + ch);
          short8 bv1 = *(const short8*)(Vc + (32 + l31) * 64 + ch);
          o0 = __builtin_amdgcn_mfma_f32_32x32x16_bf16(af, bv0, o0, 0, 0, 0);
          o1 = __builtin_amdgcn_mfma_f32_32x32x16_bf16(af, bv1, o1, 0, 0, 0);
        }
      }
      if (live1) {
        const float c1 = ((far1 ? b8 : 0.f) - m_run) * LOG2E;
#pragma unroll
        for (int ks = 0; ks < 2; ++ks) {
          float p0 = __builtin_amdgcn_exp2f(fmaf(sa1[8 * ks + 0], LOG2E, c1));
          float p1 = __builtin_amdgcn_exp2f(fmaf(sa1[8 * ks + 1], LOG2E, c1));
          float p2 = __builtin_amdgcn_exp2f(fmaf(sa1[8 * ks + 2], LOG2E, c1));
          float p3 = __builtin_amdgcn_exp2f(fmaf(sa1[8 * ks + 3], LOG2E, c1));
          float p4 = __builtin_amdgcn_exp2f(fmaf(sa1[8 * ks + 4], LOG2E, c1));
          float p5 = __builtin_amdgcn_exp2f(fmaf(sa1[8 * ks + 5], LOG2E, c1));
          float p6 = __builtin_amdgcn_exp2f(fmaf(sa1[8 * ks + 6], LOG2E, c1));
          float p7 = __builtin_amdgcn_exp2f(fmaf(sa1[8 * ks + 7], LOG2E, c1));
          rs += ((p0 + p1) + (p2 + p3)) + ((p4 + p5) + (p6 + p7));
          unsigned P00 = cvt_pk_bf16(p0, p1);
          unsigned P01 = cvt_pk_bf16(p2, p3);
          unsigned P10 = cvt_pk_bf16(p4, p5);
          unsigned P11 = cvt_pk_bf16(p6, p7);
          uint2v s0 = __builtin_amdgcn_permlane32_swap(P00, P10, false, false);
          uint2v s1 = __builtin_amdgcn_permlane32_swap(P01, P11, false, false);
          uint4v fr;
          fr[0] = s0[0]; fr[1] = s1[0]; fr[2] = s0[1]; fr[3] = s1[1];
          short8 af = *(short8*)&fr;
          int ch = ((4 + ks * 2 + hi) ^ (l31 & 7)) * 8;
          short8 bv0 = *(const short8*)(Vc + l31 * 64 + ch);
          short8 bv1 = *(const short8*)(Vc + (32 + l31) * 64 + ch);
          o0 = __builtin_amdgcn_mfma_f32_32x32x16_bf16(af, bv0, o0, 0, 0, 0);
          o1 = __builtin_amdgcn_mfma_f32_32x32x16_bf16(af, bv1, o1, 0, 0, 0);
        }
      }
      __builtin_amdgcn_s_setprio(0);
      l_run += rs;
    }
    __syncthreads();  // drains prefetch vmem + guards buffer swap
  }

  // epilogue
  float l_tot = l_run + __shfl_xor(l_run, 32, 64);  // per-q (l31-space)
  if (!partial) {
#pragma unroll
    for (int r = 0; r < 16; ++r) {
      int qrow = (r & 3) + 8 * ((r >> 2) & 3) + 4 * hi;
      float rl = __builtin_amdgcn_rcpf(__shfl(l_tot, qrow, 64));
      size_t row = grow + w * 32 + qrow;
      ao[row * 1024 + h * 64 + l31] = f2bf(o0[r] * rl);
      ao[row * 1024 + h * 64 + 32 + l31] = f2bf(o1[r] * rl);
    }
  } else {
    const int chunk = (k0 == 16) ? 1 : 0;
    const int pid = (hb * 8 + (i - 8)) * 2 + chunk;
    unsigned short* op = opart + (size_t)pid * 8192;
#pragma unroll
    for (int r = 0; r < 16; ++r) {
      int qrow = (r & 3) + 8 * ((r >> 2) & 3) + 4 * hi;
      op[(w * 32 + qrow) * 64 + l31] = f2bf(o0[r]);
      op[(w * 32 + qrow) * 64 + 32 + l31] = f2bf(o1[r]);
    }
    if (hi == 0) {
      mbuf[pid * 128 + w * 32 + l31] = m_run;
      lbuf[pid * 128 + w * 32 + l31] = l_tot;
    }
  }
}

// ------------------------------ combine partials -----------------------------
__global__ void combine_kern(const unsigned short* __restrict__ opart,
                             const float* __restrict__ mbuf,
                             const float* __restrict__ lbuf,
                             unsigned short* __restrict__ ao) {
  const int bx = blockIdx.x;  // 0..255 = (hb 32) x (j 8)
  const int hb = bx >> 3, j = bx & 7;
  const int i = 8 + j;
  const int b = hb >> 4, h = hb & 15;
  const int pid0 = bx * 2, pid1 = pid0 + 1;
  const int row = threadIdx.x >> 1;          // 0..127
  const int colg = (threadIdx.x & 1) * 32;   // 0 or 32

  float m1 = mbuf[pid0 * 128 + row], m2 = mbuf[pid1 * 128 + row];
  float l1 = lbuf[pid0 * 128 + row], l2 = lbuf[pid1 * 128 + row];
  float m = fmaxf(m1, m2);
  float s1 = __builtin_amdgcn_exp2f((m1 - m) * LOG2E);
  float s2 = __builtin_amdgcn_exp2f((m2 - m) * LOG2E);
  float linv = 1.f / fmaf(l1, s1, l2 * s2);
  s1 *= linv; s2 *= linv;

  const unsigned short* O1 = opart + (size_t)pid0 * 8192 + row * 64 + colg;
  const unsigned short* O2 = opart + (size_t)pid1 * 8192 + row * 64 + colg;
  unsigned short* dst =
      ao + ((size_t)b * 2048 + i * 128 + row) * 1024 + h * 64 + colg;
#pragma unroll
  for (int t = 0; t < 4; ++t) {
    short8 a = *(const short8*)(O1 + t * 8);
    short8 c = *(const short8*)(O2 + t * 8);
    short8 ov;
#pragma unroll
    for (int jj = 0; jj < 8; ++jj)
      ov[jj] = (short)f2bf(fmaf(bf2f((unsigned short)a[jj]), s1,
                                bf2f((unsigned short)c[jj]) * s2));
    *(short8*)(dst + t * 8) = ov;
  }
}

// --------------------------------- launcher ---------------------------------
extern "C" void kernel_launch(void* const* d_in, const int* in_sizes, int n_in,
                              void* d_out, int out_size, void* d_ws,
                              size_t ws_size, hipStream_t stream) {
  const float* k_in = (const float*)d_in[0];  // k == v == q (same x tensor)
  const float* Wk = (const float*)d_in[3];
  const float* Wv = (const float*)d_in[4];
  const float* Wq = (const float*)d_in[5];
  const float* Wo = (const float*)d_in[6];
  const float* pp = (const float*)d_in[7];

  const size_t NX = 4096u * 1024u;
  const size_t NW = 1024u * 1024u;
  unsigned short* ws = (unsigned short*)d_ws;
  unsigned short* xbf = ws;
  unsigned short* wkb = xbf + NX;
  unsigned short* wvb = wkb + NW;
  unsigned short* wqb = wvb + NW;
  unsigned short* wob = wqb + NW;
  unsigned short* khb = wob + NW;
  unsigned short* vtb = khb + NX;
  unsigned short* qhb = vtb + NX;
  unsigned short* aob = qhb + NX;
  unsigned short* opart = aob + NX;          // 512 x 8192 bf16 = 8 MB
  float* mbuf = (float*)(opart + NX);        // 512*128 f32
  float* lbuf = mbuf + 512 * 128;

  (void)in_sizes; (void)n_in; (void)out_size; (void)ws_size;

  f2bf_kern<<<dim3(4096), dim3(256), 0, stream>>>(k_in, xbf, (int)(NX / 4));
  f2bfW_kern<<<dim3(1024, 4), dim3(256), 0, stream>>>(
      Wk, wkb, Wv, wvb, Wq, wqb, Wo, wob);

  proj3_kern<<<dim3(8, 32, 3), dim3(256), 0, stream>>>(
      xbf, wkb, khb, wqb, qhb, wvb, vtb);

  attn_kern<<<dim3(32, 24), dim3(256), 0, stream>>>(qhb, khb, vtb, pp, aob,
                                                    opart, mbuf, lbuf);
  combine_kern<<<dim3(256), dim3(256), 0, stream>>>(opart, mbuf, lbuf, aob);

  gemm_out_kern<<<dim3(8, 32), dim3(256), 0, stream>>>(aob, wob, (float*)d_out);
}

// Round 9
// 115.502 us; speedup vs baseline: 1.2155x; 1.2155x over previous
//
#include <hip/hip_runtime.h>

// ---------------------------------------------------------------------------
// MultiheadAttention (B=2, S=2048, E=1024, H=16, D=64, MAX_DIST=4, causal)
//   1. f2bf_all: one conversion kernel (x once; 4 weights)
//   2. proj3: kh=[bs][e], qh=[bs][e] (*0.125), vt=[e][bs]
//   3. flash attention v9 = round-6 v5 + bias-in-registers (buckets 4..8 only;
//      0..3 are causally dead) -> LDS 40960B -> 4 blocks/CU (16 waves/CU).
//      Split-K uniform units, swapped QK^T, XOR-swizzle, dbuf K/V, defer-max.
//   4. combine partials -> ao
//   5. out = ao @ Wo^T -> fp32
// ---------------------------------------------------------------------------

using short8  = __attribute__((ext_vector_type(8))) short;
using floatx4 = __attribute__((ext_vector_type(4))) float;
using float4v = __attribute__((ext_vector_type(4))) float;
using ushort4v = __attribute__((ext_vector_type(4))) unsigned short;
using uint2v  = __attribute__((ext_vector_type(2))) unsigned int;

#define LOG2E 1.4426950408889634f

__device__ __forceinline__ unsigned short f2bf(float f) {
  unsigned u = __float_as_uint(f);
  return (unsigned short)((u + 0x7FFFu + ((u >> 16) & 1u)) >> 16);  // RNE
}
__device__ __forceinline__ float bf2f(unsigned short s) {
  return __uint_as_float(((unsigned)s) << 16);
}
__device__ __forceinline__ unsigned cvt_pk_bf16(float lo, float hi) {
  unsigned r;
  asm("v_cvt_pk_bf16_f32 %0, %1, %2" : "=v"(r) : "v"(lo), "v"(hi));
  return r;
}
__device__ __forceinline__ void gload_lds16(const void* g, void* l) {
  __builtin_amdgcn_global_load_lds(
      (const __attribute__((address_space(1))) unsigned int*)g,
      (__attribute__((address_space(3))) unsigned int*)l, 16, 0, 0);
}

// --------------------------- fp32 -> bf16 convert ---------------------------
// One kernel for all inputs: x (1M float4) + 4 weights (256K float4 each).
__global__ void f2bf_all(const float* __restrict__ x, unsigned short* xo,
                         const float* __restrict__ w0, unsigned short* o0,
                         const float* __restrict__ w1, unsigned short* o1,
                         const float* __restrict__ w2, unsigned short* o2,
                         const float* __restrict__ w3, unsigned short* o3) {
  int i = blockIdx.x * 256 + threadIdx.x;  // 0 .. 2M-1 (float4 units)
  const float* in;
  unsigned short* out;
  int off;
  if (i < (1 << 20)) {
    in = x; out = xo; off = i;
  } else {
    int j = i - (1 << 20);
    int s = j >> 18;
    off = j & ((1 << 18) - 1);
    switch (s) {
      case 0: in = w0; out = o0; break;
      case 1: in = w1; out = o1; break;
      case 2: in = w2; out = o2; break;
      default: in = w3; out = o3; break;
    }
  }
  float4v v = ((const float4v*)in)[off];
  ushort4v o;
  o[0] = f2bf(v[0]); o[1] = f2bf(v[1]); o[2] = f2bf(v[2]); o[3] = f2bf(v[3]);
  ((ushort4v*)out)[off] = o;
}

// ------------------------------ GEMM core (NT) ------------------------------
__device__ __forceinline__ void gemm_core(
    const unsigned short* __restrict__ A, const unsigned short* __restrict__ B,
    void* __restrict__ Cv, int N, int K, int mBase, int nBase, float alpha,
    bool outbf, unsigned short* As, unsigned short* Bs) {
  const int tid = threadIdx.x;
  const int lane = tid & 63;
  const int w = tid >> 6;
  const int wr = w >> 1, wc = w & 1;
  const int lr = lane & 15, lg = lane >> 4;

  floatx4 acc[4][4] = {};

  for (int k0 = 0; k0 < K; k0 += 32) {
#pragma unroll
    for (int i = 0; i < 2; ++i) {
      int idx = i * 256 + tid;
      int row = idx >> 2, c8 = (idx & 3) * 8;
      gload_lds16(A + (size_t)(mBase + row) * K + (k0 + c8), As + idx * 8);
      gload_lds16(B + (size_t)(nBase + row) * K + (k0 + c8), Bs + idx * 8);
    }
    __syncthreads();
    short8 af[4], bfr[4];
#pragma unroll
    for (int mf = 0; mf < 4; ++mf)
      af[mf] = *(const short8*)(As + (wr * 64 + mf * 16 + lr) * 32 + lg * 8);
#pragma unroll
    for (int nf = 0; nf < 4; ++nf)
      bfr[nf] = *(const short8*)(Bs + (wc * 64 + nf * 16 + lr) * 32 + lg * 8);
#pragma unroll
    for (int mf = 0; mf < 4; ++mf)
#pragma unroll
      for (int nf = 0; nf < 4; ++nf)
        acc[mf][nf] = __builtin_amdgcn_mfma_f32_16x16x32_bf16(
            af[mf], bfr[nf], acc[mf][nf], 0, 0, 0);
    __syncthreads();
  }

#pragma unroll
  for (int mf = 0; mf < 4; ++mf)
#pragma unroll
    for (int nf = 0; nf < 4; ++nf)
#pragma unroll
      for (int r = 0; r < 4; ++r) {
        size_t row = (size_t)mBase + wr * 64 + mf * 16 + lg * 4 + r;
        size_t col = (size_t)nBase + wc * 64 + nf * 16 + lr;
        float v = acc[mf][nf][r] * alpha;
        if (outbf)
          ((unsigned short*)Cv)[row * (size_t)N + col] = f2bf(v);
        else
          ((float*)Cv)[row * (size_t)N + col] = v;
      }
}

__global__ __launch_bounds__(256, 2) void proj3_kern(
    const unsigned short* __restrict__ xbf, const unsigned short* __restrict__ wkb,
    unsigned short* __restrict__ khb,
    const unsigned short* __restrict__ wqb, unsigned short* __restrict__ qhb,
    const unsigned short* __restrict__ wvb, unsigned short* __restrict__ vtb) {
  __shared__ alignas(16) unsigned short As[128 * 32];
  __shared__ alignas(16) unsigned short Bs[128 * 32];
  int z = blockIdx.z;
  if (z == 0)
    gemm_core(xbf, wkb, khb, 1024, 1024, blockIdx.y * 128, blockIdx.x * 128,
              1.0f, true, As, Bs);
  else if (z == 1)
    gemm_core(xbf, wqb, qhb, 1024, 1024, blockIdx.y * 128, blockIdx.x * 128,
              0.125f, true, As, Bs);
  else
    gemm_core(wvb, xbf, vtb, 4096, 1024, blockIdx.x * 128, blockIdx.y * 128,
              1.0f, true, As, Bs);
}

__global__ __launch_bounds__(256, 2) void gemm_out_kern(
    const unsigned short* __restrict__ A, const unsigned short* __restrict__ B,
    float* __restrict__ C) {
  __shared__ alignas(16) unsigned short As[128 * 32];
  __shared__ alignas(16) unsigned short Bs[128 * 32];
  gemm_core(A, B, C, 1024, 1024, blockIdx.y * 128, blockIdx.x * 128, 1.0f,
            false, As, Bs);
}

// ---------------------------- flash attention v9 ----------------------------
// Split-K grid (32 hb, 48 units), LPT order. 4 waves, each owns 16 q rows.
// Bias buckets 0..3 are causally dead -> only b4..b8 kept, in REGISTERS.
// LDS = 40960B exactly -> 4 blocks/CU (16 waves/CU).
__global__ __launch_bounds__(256, 4) void attn_kern(
    const unsigned short* __restrict__ qh,   // [4096][1024], pre-scaled
    const unsigned short* __restrict__ kh,   // [4096][1024]
    const unsigned short* __restrict__ vt,   // [1024][4096]
    const float* __restrict__ pp,            // [64][9]
    unsigned short* __restrict__ ao,         // [4096][1024]
    unsigned short* __restrict__ opart,      // [512][64][64] bf16 unnorm x2
    float* __restrict__ mbuf,                // [1024][64]
    float* __restrict__ lbuf) {              // [1024][64]
  __shared__ alignas(16) char smem[40960];
  unsigned short* Qs  = (unsigned short*)smem;            // 8K; later K-buf-1
  unsigned short* Vs1 = (unsigned short*)(smem + 8192);   // 8K
  unsigned short* Ks0 = (unsigned short*)(smem + 16384);  // 8K
  unsigned short* Vs0 = (unsigned short*)(smem + 24576);  // 8K
  unsigned short* Ps  = (unsigned short*)(smem + 32768);  // 8K (4 waves x 2K)
  float* ppS   = (float*)(smem + 32768);         // [9][64] f32, prologue only
  float* biasT = (float*)(smem + 35072);         // [64][6] f32, prologue only

  const int tid = threadIdx.x;
  const int lane = tid & 63;
  const int w = tid >> 6;   // 0..3, owns q rows w*16..w*16+15
  const int lr = lane & 15, lg = lane >> 4;
  const int hb = blockIdx.x;
  const int h = hb & 15, b = hb >> 4;
  const int u = blockIdx.y;

  int qt, k0, k1;
  if (u == 0)       { qt = 15;     k0 = 0;  k1 = 16; }
  else if (u <= 16) { qt = 15 + u; k0 = 0;  k1 = 16; }
  else if (u == 17) { qt = 31;     k0 = 16; k1 = 32; }
  else {
    int p = (u - 18) >> 1;
    if (((u - 18) & 1) == 0) { qt = 14 - p; k0 = 0;  k1 = qt + 1; }
    else                     { qt = 30 - p; k0 = 16; k1 = qt + 1; }
  }
  const bool partial = (qt >= 16);
  const int qbase = qt * 64;
  const size_t bsQ = (size_t)b * 2048 + qbase;

  const unsigned short* khB = kh + ((size_t)b * 2048) * 1024 + h * 64;
  const unsigned short* vtB = vt + ((size_t)h * 64) * 4096 + b * 2048;

  auto stage_kv = [&](int kbase, unsigned short* Kd, unsigned short* Vd) {
#pragma unroll
    for (int i = 0; i < 2; ++i) {
      int idx = i * 256 + tid;
      int row = idx >> 3, pc = idx & 7;
      int cl = pc ^ (row & 7);  // pre-swizzled global source
      gload_lds16(khB + ((size_t)(kbase + row) << 10) + cl * 8, Kd + idx * 8);
      gload_lds16(vtB + ((size_t)row << 12) + kbase + cl * 8, Vd + idx * 8);
    }
  };

  // prologue: stage Q (linear), pp table, first K/V tile
#pragma unroll
  for (int i = 0; i < 2; ++i) {
    int idx = i * 256 + tid;
    int row = idx >> 3, c8 = (idx & 7) * 8;
    gload_lds16(qh + (bsQ + row) * 1024 + h * 64 + c8, Qs + idx * 8);
  }
  for (int idx = tid; idx < 576; idx += 256) {
    int r = idx >> 6, d = idx & 63;
    ppS[r * 64 + d] = pp[d * 9 + r];
  }
  stage_kv(k0 * 64, Ks0, Vs0);
  __syncthreads();

  // Q fragments (B-operand): lane holds Q[q = w*16+lr][d = c*32+lg*8+j]
  const int qrowL = w * 16 + lr;
  short8 aq[2];
#pragma unroll
  for (int c = 0; c < 2; ++c)
    aq[c] = *(const short8*)(Qs + qrowL * 64 + c * 32 + lg * 8);

  // rel-pos bias (buckets 4..8 only; 0..3 causally dead):
  // biasT[row][rr] = sum_d qh_scaled[row][d] * p[d][rr+4]
  for (int idx = tid; idx < 320; idx += 256) {
    int row = idx / 5, rr = idx - row * 5;
    const unsigned short* qrow = Qs + row * 64;
    const float* pr = ppS + (rr + 4) * 64;
    float s = 0.f;
#pragma unroll
    for (int d8 = 0; d8 < 8; ++d8) {
      short8 qv = *(const short8*)(qrow + d8 * 8);
#pragma unroll
      for (int j = 0; j < 8; ++j)
        s += bf2f((unsigned short)qv[j]) * pr[d8 * 8 + j];
    }
    biasT[row * 6 + rr] = s;
  }
  __syncthreads();

  // per-lane bias registers (lane's q-row = qrowL; lg groups broadcast)
  const float b4 = biasT[qrowL * 6 + 0];
  const float b5 = biasT[qrowL * 6 + 1];
  const float b6 = biasT[qrowL * 6 + 2];
  const float b7 = biasT[qrowL * 6 + 3];
  const float b8 = biasT[qrowL * 6 + 4];
  __syncthreads();  // ppS/biasT dead -> Ps region free for P tiles

  const int q_glob = qbase + w * 16 + lr;
  unsigned short* Pw = Ps + w * 1024;

  float m_run = -1e30f, l_run = 0.f;
  floatx4 o[4] = {};

  for (int kt = k0; kt < k1; ++kt) {
    const int kbase = kt * 64;
    const int cur = (kt - k0) & 1;
    unsigned short* Kc = cur ? Qs : Ks0;
    unsigned short* Vc = cur ? Vs1 : Vs0;
    if (kt + 1 < k1)
      stage_kv(kbase + 64, cur ? Ks0 : Qs, cur ? Vs0 : Vs1);  // prefetch

    // S^T = K @ Q^T : lane holds S[k = kf*16+lg*4+r][q = w*16+lr]
    floatx4 sa[4] = {};
    __builtin_amdgcn_s_setprio(1);
#pragma unroll
    for (int kf = 0; kf < 4; ++kf)
#pragma unroll
      for (int c = 0; c < 2; ++c) {
        int row = kf * 16 + lr;
        short8 ak = *(const short8*)(Kc + row * 64 +
                                     (((c * 4 + lg) ^ (lr & 7)) * 8));
        sa[kf] = __builtin_amdgcn_mfma_f32_16x16x32_bf16(ak, aq[c], sa[kf],
                                                         0, 0, 0);
      }
    __builtin_amdgcn_s_setprio(0);

    // bias + causal mask (registers only)
    float bext;
    if (qbase + w * 16 >= kbase + 67) {  // whole wave sub-tile at dist >= 4
      bext = b8;                         // folded into exp arg below
    } else {
      bext = 0.f;
#pragma unroll
      for (int kf = 0; kf < 4; ++kf)
#pragma unroll
        for (int r = 0; r < 4; ++r) {
          int dq = q_glob - (kbase + kf * 16 + lg * 4 + r);
          float bb = (dq >= 4) ? b8
                   : (dq == 0 ? b4 : (dq == 1 ? b5 : (dq == 2 ? b6 : b7)));
          sa[kf][r] = (dq < 0) ? -1e30f : (sa[kf][r] + bb);
        }
    }

    // online softmax with defer-max (THR=8)
    float mx = -1e30f;
#pragma unroll
    for (int kf = 0; kf < 4; ++kf)
#pragma unroll
      for (int r = 0; r < 4; ++r) mx = fmaxf(mx, sa[kf][r]);
    mx += bext;
    mx = fmaxf(mx, __shfl_xor(mx, 16, 64));
    mx = fmaxf(mx, __shfl_xor(mx, 32, 64));
    if (__any(mx > m_run + 8.f)) {
      float mn = fmaxf(m_run, mx);
      float al = __builtin_amdgcn_exp2f((m_run - mn) * LOG2E);
      m_run = mn;
      l_run *= al;
      float alo[4];
#pragma unroll
      for (int r = 0; r < 4; ++r) alo[r] = __shfl(al, lg * 4 + r, 64);
#pragma unroll
      for (int df = 0; df < 4; ++df)
#pragma unroll
        for (int r = 0; r < 4; ++r) o[df][r] *= alo[r];
    }

    const float c1 = (bext - m_run) * LOG2E;
    float rs = 0.f;
#pragma unroll
    for (int kf = 0; kf < 4; ++kf) {
      float p0 = __builtin_amdgcn_exp2f(fmaf(sa[kf][0], LOG2E, c1));
      float p1 = __builtin_amdgcn_exp2f(fmaf(sa[kf][1], LOG2E, c1));
      float p2 = __builtin_amdgcn_exp2f(fmaf(sa[kf][2], LOG2E, c1));
      float p3 = __builtin_amdgcn_exp2f(fmaf(sa[kf][3], LOG2E, c1));
      rs += (p0 + p1) + (p2 + p3);
      uint2v pk;
      pk[0] = cvt_pk_bf16(p0, p1);
      pk[1] = cvt_pk_bf16(p2, p3);
      int phys = (kf * 2 + (lg >> 1)) ^ (lr & 7);
      *(uint2v*)(Pw + lr * 64 + phys * 8 + (lg & 1) * 4) = pk;
    }
    rs += __shfl_xor(rs, 16, 64);
    rs += __shfl_xor(rs, 32, 64);
    l_run += rs;

    // O += P @ V
    __builtin_amdgcn_s_setprio(1);
#pragma unroll
    for (int c = 0; c < 2; ++c) {
      short8 pa = *(const short8*)(Pw + lr * 64 +
                                   (((c * 4 + lg) ^ (lr & 7)) * 8));
#pragma unroll
      for (int df = 0; df < 4; ++df) {
        int row = df * 16 + lr;
        short8 bv = *(const short8*)(Vc + row * 64 +
                                     (((c * 4 + lg) ^ (lr & 7)) * 8));
        o[df] = __builtin_amdgcn_mfma_f32_16x16x32_bf16(pa, bv, o[df],
                                                        0, 0, 0);
      }
    }
    __builtin_amdgcn_s_setprio(0);
    __syncthreads();  // drains prefetch vmem + guards buffer swap
  }

  // epilogue: lane holds O[q = w*16+lg*4+r][d = df*16+lr]
  if (!partial) {
    float rl[4];
#pragma unroll
    for (int r = 0; r < 4; ++r)
      rl[r] = __builtin_amdgcn_rcpf(__shfl(l_run, lg * 4 + r, 64));
    const size_t outRow0 = bsQ + w * 16 + lg * 4;
#pragma unroll
    for (int df = 0; df < 4; ++df)
#pragma unroll
      for (int r = 0; r < 4; ++r)
        ao[(outRow0 + r) * 1024 + h * 64 + df * 16 + lr] =
            f2bf(o[df][r] * rl[r]);
  } else {
    const int pid = (hb * 16 + (qt - 16)) * 2 + (k0 == 16 ? 1 : 0);
    unsigned short* op = opart + (size_t)pid * 4096;
#pragma unroll
    for (int df = 0; df < 4; ++df)
#pragma unroll
      for (int r = 0; r < 4; ++r)
        op[(w * 16 + lg * 4 + r) * 64 + df * 16 + lr] = f2bf(o[df][r]);
    if (lg == 0) {
      mbuf[pid * 64 + w * 16 + lr] = m_run;
      lbuf[pid * 64 + w * 16 + lr] = l_run;
    }
  }
}

// ------------------------------ combine partials -----------------------------
__global__ void combine_kern(const unsigned short* __restrict__ opart,
                             const float* __restrict__ mbuf,
                             const float* __restrict__ lbuf,
                             unsigned short* __restrict__ ao) {
  const int t = blockIdx.x;         // 0..511
  const int hb = t >> 4;
  const int qtl = t & 15;
  const int qt = 16 + qtl;
  const int b = hb >> 4, h = hb & 15;
  const int pid0 = (hb * 16 + qtl) * 2, pid1 = pid0 + 1;
  const int row = threadIdx.x >> 2;
  const int colg = (threadIdx.x & 3) * 16;

  float m1 = mbuf[pid0 * 64 + row], m2 = mbuf[pid1 * 64 + row];
  float l1 = lbuf[pid0 * 64 + row], l2 = lbuf[pid1 * 64 + row];
  float m = fmaxf(m1, m2);
  float s1 = __builtin_amdgcn_exp2f((m1 - m) * LOG2E);
  float s2 = __builtin_amdgcn_exp2f((m2 - m) * LOG2E);
  float linv = 1.f / fmaf(l1, s1, l2 * s2);
  s1 *= linv; s2 *= linv;

  const unsigned short* O1 = opart + (size_t)pid0 * 4096 + row * 64 + colg;
  const unsigned short* O2 = opart + (size_t)pid1 * 4096 + row * 64 + colg;
  unsigned short* dst =
      ao + ((size_t)b * 2048 + qt * 64 + row) * 1024 + h * 64 + colg;
#pragma unroll
  for (int i = 0; i < 2; ++i) {
    short8 a = *(const short8*)(O1 + i * 8);
    short8 c = *(const short8*)(O2 + i * 8);
    short8 ov;
#pragma unroll
    for (int j = 0; j < 8; ++j)
      ov[j] = (short)f2bf(fmaf(bf2f((unsigned short)a[j]), s1,
                               bf2f((unsigned short)c[j]) * s2));
    *(short8*)(dst + i * 8) = ov;
  }
}

// --------------------------------- launcher ---------------------------------
extern "C" void kernel_launch(void* const* d_in, const int* in_sizes, int n_in,
                              void* d_out, int out_size, void* d_ws,
                              size_t ws_size, hipStream_t stream) {
  const float* k_in = (const float*)d_in[0];  // k == v == q (same x tensor)
  const float* Wk = (const float*)d_in[3];
  const float* Wv = (const float*)d_in[4];
  const float* Wq = (const float*)d_in[5];
  const float* Wo = (const float*)d_in[6];
  const float* pp = (const float*)d_in[7];

  const size_t NX = 4096u * 1024u;
  const size_t NW = 1024u * 1024u;
  unsigned short* ws = (unsigned short*)d_ws;
  unsigned short* xbf = ws;
  unsigned short* wkb = xbf + NX;
  unsigned short* wvb = wkb + NW;
  unsigned short* wqb = wvb + NW;
  unsigned short* wob = wqb + NW;
  unsigned short* khb = wob + NW;
  unsigned short* vtb = khb + NX;
  unsigned short* qhb = vtb + NX;
  unsigned short* aob = qhb + NX;
  unsigned short* opart = aob + NX;          // 1024 tiles x 4096 bf16 = 8 MB
  float* mbuf = (float*)(opart + NX);        // 1024*64 f32
  float* lbuf = mbuf + 1024 * 64;

  (void)in_sizes; (void)n_in; (void)out_size; (void)ws_size;

  f2bf_all<<<dim3(8192), dim3(256), 0, stream>>>(
      k_in, xbf, Wk, wkb, Wv, wvb, Wq, wqb, Wo, wob);

  proj3_kern<<<dim3(8, 32, 3), dim3(256), 0, stream>>>(
      xbf, wkb, khb, wqb, qhb, wvb, vtb);

  attn_kern<<<dim3(32, 48), dim3(256), 0, stream>>>(qhb, khb, vtb, pp, aob,
                                                    opart, mbuf, lbuf);
  combine_kern<<<dim3(512), dim3(256), 0, stream>>>(opart, mbuf, lbuf, aob);

  gemm_out_kern<<<dim3(8, 32), dim3(256), 0, stream>>>(aob, wob, (float*)d_out);
}

// Round 10
// 104.914 us; speedup vs baseline: 1.3382x; 1.1009x over previous
//
#include <hip/hip_runtime.h>

// ---------------------------------------------------------------------------
// MultiheadAttention (B=2, S=2048, E=1024, H=16, D=64, MAX_DIST=4, causal)
//   1. f2bf_all: one conversion kernel (x once; 4 weights)
//   2. proj3: kh=[bs][e], qh=[bs][e] (*0.125), vt=[e][bs]  (BK=64, swizzled)
//   3. flash attention v9 (round-9, unchanged): split-K, 4 blocks/CU,
//      bias-in-registers, swapped QK^T, XOR-swizzle, dbuf K/V, defer-max
//   4. combine partials -> ao
//   5. out = ao @ Wo^T -> fp32 (64x128 tile, 512 blocks = 2/CU, BK=64)
// ---------------------------------------------------------------------------

using short8  = __attribute__((ext_vector_type(8))) short;
using floatx4 = __attribute__((ext_vector_type(4))) float;
using float4v = __attribute__((ext_vector_type(4))) float;
using ushort4v = __attribute__((ext_vector_type(4))) unsigned short;
using uint2v  = __attribute__((ext_vector_type(2))) unsigned int;

#define LOG2E 1.4426950408889634f

__device__ __forceinline__ unsigned short f2bf(float f) {
  unsigned u = __float_as_uint(f);
  return (unsigned short)((u + 0x7FFFu + ((u >> 16) & 1u)) >> 16);  // RNE
}
__device__ __forceinline__ float bf2f(unsigned short s) {
  return __uint_as_float(((unsigned)s) << 16);
}
__device__ __forceinline__ unsigned cvt_pk_bf16(float lo, float hi) {
  unsigned r;
  asm("v_cvt_pk_bf16_f32 %0, %1, %2" : "=v"(r) : "v"(lo), "v"(hi));
  return r;
}
__device__ __forceinline__ void gload_lds16(const void* g, void* l) {
  __builtin_amdgcn_global_load_lds(
      (const __attribute__((address_space(1))) unsigned int*)g,
      (__attribute__((address_space(3))) unsigned int*)l, 16, 0, 0);
}

// --------------------------- fp32 -> bf16 convert ---------------------------
__global__ void f2bf_all(const float* __restrict__ x, unsigned short* xo,
                         const float* __restrict__ w0, unsigned short* o0,
                         const float* __restrict__ w1, unsigned short* o1,
                         const float* __restrict__ w2, unsigned short* o2,
                         const float* __restrict__ w3, unsigned short* o3) {
  int i = blockIdx.x * 256 + threadIdx.x;  // 0 .. 2M-1 (float4 units)
  const float* in;
  unsigned short* out;
  int off;
  if (i < (1 << 20)) {
    in = x; out = xo; off = i;
  } else {
    int j = i - (1 << 20);
    int s = j >> 18;
    off = j & ((1 << 18) - 1);
    switch (s) {
      case 0: in = w0; out = o0; break;
      case 1: in = w1; out = o1; break;
      case 2: in = w2; out = o2; break;
      default: in = w3; out = o3; break;
    }
  }
  float4v v = ((const float4v*)in)[off];
  ushort4v o;
  o[0] = f2bf(v[0]); o[1] = f2bf(v[1]); o[2] = f2bf(v[2]); o[3] = f2bf(v[3]);
  ((ushort4v*)out)[off] = o;
}

// ------------------------- GEMM core (NT, BK=64, swz) ------------------------
// C[m][n] = alpha * sum_k A[m][k]*B[n][k].  Tile TM x 128, BK=64.
// 4 waves (2x2); wave sub-tile (TM/2) x 64. XOR-swizzled LDS (16B chunks,
// chunk ^= row&7; global source pre-swizzled per rule #21).
template <int TM>
__device__ __forceinline__ void gemm_core64(
    const unsigned short* __restrict__ A, const unsigned short* __restrict__ B,
    void* __restrict__ Cv, int N, int K, int mBase, int nBase, float alpha,
    bool outbf, unsigned short* As, unsigned short* Bs) {
  const int tid = threadIdx.x;
  const int lane = tid & 63;
  const int w = tid >> 6;
  const int wr = w >> 1, wc = w & 1;
  const int lr = lane & 15, lg = lane >> 4;
  constexpr int NMF = TM / 32;  // M-fragments per wave (4 or 2)

  floatx4 acc[NMF][4] = {};

  for (int k0 = 0; k0 < K; k0 += 64) {
#pragma unroll
    for (int i = 0; i < TM / 32; ++i) {  // A: TM rows x 8 chunks
      int idx = i * 256 + tid;
      int row = idx >> 3, pc = idx & 7;
      int cl = pc ^ (row & 7);
      gload_lds16(A + (size_t)(mBase + row) * K + k0 + cl * 8, As + idx * 8);
    }
#pragma unroll
    for (int i = 0; i < 4; ++i) {  // B: 128 rows x 8 chunks
      int idx = i * 256 + tid;
      int row = idx >> 3, pc = idx & 7;
      int cl = pc ^ (row & 7);
      gload_lds16(B + (size_t)(nBase + row) * K + k0 + cl * 8, Bs + idx * 8);
    }
    __syncthreads();
#pragma unroll
    for (int c = 0; c < 2; ++c) {
      short8 af[NMF], bfr[4];
#pragma unroll
      for (int mf = 0; mf < NMF; ++mf) {
        int row = wr * (TM / 2) + mf * 16 + lr;
        af[mf] = *(const short8*)(As + row * 64 + (((c * 4 + lg) ^ (lr & 7)) * 8));
      }
#pragma unroll
      for (int nf = 0; nf < 4; ++nf) {
        int row = wc * 64 + nf * 16 + lr;
        bfr[nf] = *(const short8*)(Bs + row * 64 + (((c * 4 + lg) ^ (lr & 7)) * 8));
      }
#pragma unroll
      for (int mf = 0; mf < NMF; ++mf)
#pragma unroll
        for (int nf = 0; nf < 4; ++nf)
          acc[mf][nf] = __builtin_amdgcn_mfma_f32_16x16x32_bf16(
              af[mf], bfr[nf], acc[mf][nf], 0, 0, 0);
    }
    __syncthreads();
  }

#pragma unroll
  for (int mf = 0; mf < NMF; ++mf)
#pragma unroll
    for (int nf = 0; nf < 4; ++nf)
#pragma unroll
      for (int r = 0; r < 4; ++r) {
        size_t row = (size_t)mBase + wr * (TM / 2) + mf * 16 + lg * 4 + r;
        size_t col = (size_t)nBase + wc * 64 + nf * 16 + lr;
        float v = acc[mf][nf][r] * alpha;
        if (outbf)
          ((unsigned short*)Cv)[row * (size_t)N + col] = f2bf(v);
        else
          ((float*)Cv)[row * (size_t)N + col] = v;
      }
}

__global__ __launch_bounds__(256, 2) void proj3_kern(
    const unsigned short* __restrict__ xbf, const unsigned short* __restrict__ wkb,
    unsigned short* __restrict__ khb,
    const unsigned short* __restrict__ wqb, unsigned short* __restrict__ qhb,
    const unsigned short* __restrict__ wvb, unsigned short* __restrict__ vtb) {
  __shared__ alignas(16) unsigned short As[128 * 64];
  __shared__ alignas(16) unsigned short Bs[128 * 64];
  int z = blockIdx.z;
  if (z == 0)
    gemm_core64<128>(xbf, wkb, khb, 1024, 1024, blockIdx.y * 128,
                     blockIdx.x * 128, 1.0f, true, As, Bs);
  else if (z == 1)
    gemm_core64<128>(xbf, wqb, qhb, 1024, 1024, blockIdx.y * 128,
                     blockIdx.x * 128, 0.125f, true, As, Bs);
  else
    gemm_core64<128>(wvb, xbf, vtb, 4096, 1024, blockIdx.x * 128,
                     blockIdx.y * 128, 1.0f, true, As, Bs);
}

__global__ __launch_bounds__(256, 2) void gemm_out_kern(
    const unsigned short* __restrict__ A, const unsigned short* __restrict__ B,
    float* __restrict__ C) {
  __shared__ alignas(16) unsigned short As[64 * 64];
  __shared__ alignas(16) unsigned short Bs[128 * 64];
  gemm_core64<64>(A, B, C, 1024, 1024, blockIdx.y * 64, blockIdx.x * 128,
                  1.0f, false, As, Bs);
}

// ---------------------------- flash attention v9 ----------------------------
// (unchanged from round 9 — 51 us, occupancy 30%)
__global__ __launch_bounds__(256, 4) void attn_kern(
    const unsigned short* __restrict__ qh,   // [4096][1024], pre-scaled
    const unsigned short* __restrict__ kh,   // [4096][1024]
    const unsigned short* __restrict__ vt,   // [1024][4096]
    const float* __restrict__ pp,            // [64][9]
    unsigned short* __restrict__ ao,         // [4096][1024]
    unsigned short* __restrict__ opart,      // partials
    float* __restrict__ mbuf,
    float* __restrict__ lbuf) {
  __shared__ alignas(16) char smem[40960];
  unsigned short* Qs  = (unsigned short*)smem;            // 8K; later K-buf-1
  unsigned short* Vs1 = (unsigned short*)(smem + 8192);   // 8K
  unsigned short* Ks0 = (unsigned short*)(smem + 16384);  // 8K
  unsigned short* Vs0 = (unsigned short*)(smem + 24576);  // 8K
  unsigned short* Ps  = (unsigned short*)(smem + 32768);  // 8K (4 waves x 2K)
  float* ppS   = (float*)(smem + 32768);         // [9][64] f32, prologue only
  float* biasT = (float*)(smem + 35072);         // [64][6] f32, prologue only

  const int tid = threadIdx.x;
  const int lane = tid & 63;
  const int w = tid >> 6;   // 0..3, owns q rows w*16..w*16+15
  const int lr = lane & 15, lg = lane >> 4;
  const int hb = blockIdx.x;
  const int h = hb & 15, b = hb >> 4;
  const int u = blockIdx.y;

  int qt, k0, k1;
  if (u == 0)       { qt = 15;     k0 = 0;  k1 = 16; }
  else if (u <= 16) { qt = 15 + u; k0 = 0;  k1 = 16; }
  else if (u == 17) { qt = 31;     k0 = 16; k1 = 32; }
  else {
    int p = (u - 18) >> 1;
    if (((u - 18) & 1) == 0) { qt = 14 - p; k0 = 0;  k1 = qt + 1; }
    else                     { qt = 30 - p; k0 = 16; k1 = qt + 1; }
  }
  const bool partial = (qt >= 16);
  const int qbase = qt * 64;
  const size_t bsQ = (size_t)b * 2048 + qbase;

  const unsigned short* khB = kh + ((size_t)b * 2048) * 1024 + h * 64;
  const unsigned short* vtB = vt + ((size_t)h * 64) * 4096 + b * 2048;

  auto stage_kv = [&](int kbase, unsigned short* Kd, unsigned short* Vd) {
#pragma unroll
    for (int i = 0; i < 2; ++i) {
      int idx = i * 256 + tid;
      int row = idx >> 3, pc = idx & 7;
      int cl = pc ^ (row & 7);  // pre-swizzled global source
      gload_lds16(khB + ((size_t)(kbase + row) << 10) + cl * 8, Kd + idx * 8);
      gload_lds16(vtB + ((size_t)row << 12) + kbase + cl * 8, Vd + idx * 8);
    }
  };

  // prologue: stage Q (linear), pp table, first K/V tile
#pragma unroll
  for (int i = 0; i < 2; ++i) {
    int idx = i * 256 + tid;
    int row = idx >> 3, c8 = (idx & 7) * 8;
    gload_lds16(qh + (bsQ + row) * 1024 + h * 64 + c8, Qs + idx * 8);
  }
  for (int idx = tid; idx < 576; idx += 256) {
    int r = idx >> 6, d = idx & 63;
    ppS[r * 64 + d] = pp[d * 9 + r];
  }
  stage_kv(k0 * 64, Ks0, Vs0);
  __syncthreads();

  // Q fragments (B-operand): lane holds Q[q = w*16+lr][d = c*32+lg*8+j]
  const int qrowL = w * 16 + lr;
  short8 aq[2];
#pragma unroll
  for (int c = 0; c < 2; ++c)
    aq[c] = *(const short8*)(Qs + qrowL * 64 + c * 32 + lg * 8);

  // rel-pos bias (buckets 4..8 only; 0..3 causally dead)
  for (int idx = tid; idx < 320; idx += 256) {
    int row = idx / 5, rr = idx - row * 5;
    const unsigned short* qrow = Qs + row * 64;
    const float* pr = ppS + (rr + 4) * 64;
    float s = 0.f;
#pragma unroll
    for (int d8 = 0; d8 < 8; ++d8) {
      short8 qv = *(const short8*)(qrow + d8 * 8);
#pragma unroll
      for (int j = 0; j < 8; ++j)
        s += bf2f((unsigned short)qv[j]) * pr[d8 * 8 + j];
    }
    biasT[row * 6 + rr] = s;
  }
  __syncthreads();

  const float b4 = biasT[qrowL * 6 + 0];
  const float b5 = biasT[qrowL * 6 + 1];
  const float b6 = biasT[qrowL * 6 + 2];
  const float b7 = biasT[qrowL * 6 + 3];
  const float b8 = biasT[qrowL * 6 + 4];
  __syncthreads();  // ppS/biasT dead -> Ps region free for P tiles

  const int q_glob = qbase + w * 16 + lr;
  unsigned short* Pw = Ps + w * 1024;

  float m_run = -1e30f, l_run = 0.f;
  floatx4 o[4] = {};

  for (int kt = k0; kt < k1; ++kt) {
    const int kbase = kt * 64;
    const int cur = (kt - k0) & 1;
    unsigned short* Kc = cur ? Qs : Ks0;
    unsigned short* Vc = cur ? Vs1 : Vs0;
    if (kt + 1 < k1)
      stage_kv(kbase + 64, cur ? Ks0 : Qs, cur ? Vs0 : Vs1);  // prefetch

    // S^T = K @ Q^T : lane holds S[k = kf*16+lg*4+r][q = w*16+lr]
    floatx4 sa[4] = {};
    __builtin_amdgcn_s_setprio(1);
#pragma unroll
    for (int kf = 0; kf < 4; ++kf)
#pragma unroll
      for (int c = 0; c < 2; ++c) {
        int row = kf * 16 + lr;
        short8 ak = *(const short8*)(Kc + row * 64 +
                                     (((c * 4 + lg) ^ (lr & 7)) * 8));
        sa[kf] = __builtin_amdgcn_mfma_f32_16x16x32_bf16(ak, aq[c], sa[kf],
                                                         0, 0, 0);
      }
    __builtin_amdgcn_s_setprio(0);

    // bias + causal mask (registers only)
    float bext;
    if (qbase + w * 16 >= kbase + 67) {
      bext = b8;
    } else {
      bext = 0.f;
#pragma unroll
      for (int kf = 0; kf < 4; ++kf)
#pragma unroll
        for (int r = 0; r < 4; ++r) {
          int dq = q_glob - (kbase + kf * 16 + lg * 4 + r);
          float bb = (dq >= 4) ? b8
                   : (dq == 0 ? b4 : (dq == 1 ? b5 : (dq == 2 ? b6 : b7)));
          sa[kf][r] = (dq < 0) ? -1e30f : (sa[kf][r] + bb);
        }
    }

    // online softmax with defer-max (THR=8)
    float mx = -1e30f;
#pragma unroll
    for (int kf = 0; kf < 4; ++kf)
#pragma unroll
      for (int r = 0; r < 4; ++r) mx = fmaxf(mx, sa[kf][r]);
    mx += bext;
    mx = fmaxf(mx, __shfl_xor(mx, 16, 64));
    mx = fmaxf(mx, __shfl_xor(mx, 32, 64));
    if (__any(mx > m_run + 8.f)) {
      float mn = fmaxf(m_run, mx);
      float al = __builtin_amdgcn_exp2f((m_run - mn) * LOG2E);
      m_run = mn;
      l_run *= al;
      float alo[4];
#pragma unroll
      for (int r = 0; r < 4; ++r) alo[r] = __shfl(al, lg * 4 + r, 64);
#pragma unroll
      for (int df = 0; df < 4; ++df)
#pragma unroll
        for (int r = 0; r < 4; ++r) o[df][r] *= alo[r];
    }

    const float c1 = (bext - m_run) * LOG2E;
    float rs = 0.f;
#pragma unroll
    for (int kf = 0; kf < 4; ++kf) {
      float p0 = __builtin_amdgcn_exp2f(fmaf(sa[kf][0], LOG2E, c1));
      float p1 = __builtin_amdgcn_exp2f(fmaf(sa[kf][1], LOG2E, c1));
      float p2 = __builtin_amdgcn_exp2f(fmaf(sa[kf][2], LOG2E, c1));
      float p3 = __builtin_amdgcn_exp2f(fmaf(sa[kf][3], LOG2E, c1));
      rs += (p0 + p1) + (p2 + p3);
      uint2v pk;
      pk[0] = cvt_pk_bf16(p0, p1);
      pk[1] = cvt_pk_bf16(p2, p3);
      int phys = (kf * 2 + (lg >> 1)) ^ (lr & 7);
      *(uint2v*)(Pw + lr * 64 + phys * 8 + (lg & 1) * 4) = pk;
    }
    rs += __shfl_xor(rs, 16, 64);
    rs += __shfl_xor(rs, 32, 64);
    l_run += rs;

    // O += P @ V
    __builtin_amdgcn_s_setprio(1);
#pragma unroll
    for (int c = 0; c < 2; ++c) {
      short8 pa = *(const short8*)(Pw + lr * 64 +
                                   (((c * 4 + lg) ^ (lr & 7)) * 8));
#pragma unroll
      for (int df = 0; df < 4; ++df) {
        int row = df * 16 + lr;
        short8 bv = *(const short8*)(Vc + row * 64 +
                                     (((c * 4 + lg) ^ (lr & 7)) * 8));
        o[df] = __builtin_amdgcn_mfma_f32_16x16x32_bf16(pa, bv, o[df],
                                                        0, 0, 0);
      }
    }
    __builtin_amdgcn_s_setprio(0);
    __syncthreads();  // drains prefetch vmem + guards buffer swap
  }

  // epilogue
  if (!partial) {
    float rl[4];
#pragma unroll
    for (int r = 0; r < 4; ++r)
      rl[r] = __builtin_amdgcn_rcpf(__shfl(l_run, lg * 4 + r, 64));
    const size_t outRow0 = bsQ + w * 16 + lg * 4;
#pragma unroll
    for (int df = 0; df < 4; ++df)
#pragma unroll
      for (int r = 0; r < 4; ++r)
        ao[(outRow0 + r) * 1024 + h * 64 + df * 16 + lr] =
            f2bf(o[df][r] * rl[r]);
  } else {
    const int pid = (hb * 16 + (qt - 16)) * 2 + (k0 == 16 ? 1 : 0);
    unsigned short* op = opart + (size_t)pid * 4096;
#pragma unroll
    for (int df = 0; df < 4; ++df)
#pragma unroll
      for (int r = 0; r < 4; ++r)
        op[(w * 16 + lg * 4 + r) * 64 + df * 16 + lr] = f2bf(o[df][r]);
    if (lg == 0) {
      mbuf[pid * 64 + w * 16 + lr] = m_run;
      lbuf[pid * 64 + w * 16 + lr] = l_run;
    }
  }
}

// ------------------------------ combine partials -----------------------------
__global__ void combine_kern(const unsigned short* __restrict__ opart,
                             const float* __restrict__ mbuf,
                             const float* __restrict__ lbuf,
                             unsigned short* __restrict__ ao) {
  const int t = blockIdx.x;         // 0..511
  const int hb = t >> 4;
  const int qtl = t & 15;
  const int qt = 16 + qtl;
  const int b = hb >> 4, h = hb & 15;
  const int pid0 = (hb * 16 + qtl) * 2, pid1 = pid0 + 1;
  const int row = threadIdx.x >> 2;
  const int colg = (threadIdx.x & 3) * 16;

  float m1 = mbuf[pid0 * 64 + row], m2 = mbuf[pid1 * 64 + row];
  float l1 = lbuf[pid0 * 64 + row], l2 = lbuf[pid1 * 64 + row];
  float m = fmaxf(m1, m2);
  float s1 = __builtin_amdgcn_exp2f((m1 - m) * LOG2E);
  float s2 = __builtin_amdgcn_exp2f((m2 - m) * LOG2E);
  float linv = 1.f / fmaf(l1, s1, l2 * s2);
  s1 *= linv; s2 *= linv;

  const unsigned short* O1 = opart + (size_t)pid0 * 4096 + row * 64 + colg;
  const unsigned short* O2 = opart + (size_t)pid1 * 4096 + row * 64 + colg;
  unsigned short* dst =
      ao + ((size_t)b * 2048 + qt * 64 + row) * 1024 + h * 64 + colg;
#pragma unroll
  for (int i = 0; i < 2; ++i) {
    short8 a = *(const short8*)(O1 + i * 8);
    short8 c = *(const short8*)(O2 + i * 8);
    short8 ov;
#pragma unroll
    for (int j = 0; j < 8; ++j)
      ov[j] = (short)f2bf(fmaf(bf2f((unsigned short)a[j]), s1,
                               bf2f((unsigned short)c[j]) * s2));
    *(short8*)(dst + i * 8) = ov;
  }
}

// --------------------------------- launcher ---------------------------------
extern "C" void kernel_launch(void* const* d_in, const int* in_sizes, int n_in,
                              void* d_out, int out_size, void* d_ws,
                              size_t ws_size, hipStream_t stream) {
  const float* k_in = (const float*)d_in[0];  // k == v == q (same x tensor)
  const float* Wk = (const float*)d_in[3];
  const float* Wv = (const float*)d_in[4];
  const float* Wq = (const float*)d_in[5];
  const float* Wo = (const float*)d_in[6];
  const float* pp = (const float*)d_in[7];

  const size_t NX = 4096u * 1024u;
  const size_t NW = 1024u * 1024u;
  unsigned short* ws = (unsigned short*)d_ws;
  unsigned short* xbf = ws;
  unsigned short* wkb = xbf + NX;
  unsigned short* wvb = wkb + NW;
  unsigned short* wqb = wvb + NW;
  unsigned short* wob = wqb + NW;
  unsigned short* khb = wob + NW;
  unsigned short* vtb = khb + NX;
  unsigned short* qhb = vtb + NX;
  unsigned short* aob = qhb + NX;
  unsigned short* opart = aob + NX;          // 1024 tiles x 4096 bf16 = 8 MB
  float* mbuf = (float*)(opart + NX);        // 1024*64 f32
  float* lbuf = mbuf + 1024 * 64;

  (void)in_sizes; (void)n_in; (void)out_size; (void)ws_size;

  f2bf_all<<<dim3(8192), dim3(256), 0, stream>>>(
      k_in, xbf, Wk, wkb, Wv, wvb, Wq, wqb, Wo, wob);

  proj3_kern<<<dim3(8, 32, 3), dim3(256), 0, stream>>>(
      xbf, wkb, khb, wqb, qhb, wvb, vtb);

  attn_kern<<<dim3(32, 48), dim3(256), 0, stream>>>(qhb, khb, vtb, pp, aob,
                                                    opart, mbuf, lbuf);
  combine_kern<<<dim3(512), dim3(256), 0, stream>>>(opart, mbuf, lbuf, aob);

  gemm_out_kern<<<dim3(8, 64), dim3(256), 0, stream>>>(aob, wob, (float*)d_out);
}